// Round 1
// baseline (22950.620 us; speedup 1.0000x reference)
//
#include <hip/hip_runtime.h>
#include <cstdint>
#include <cstddef>

// ---------------- problem constants ----------------
#define TSTEPS 2000
#define NB     256      // batch
#define HID    128
#define CIN    14
#define NGRP   16       // row groups
#define RG     16       // rows per group
#define BPG    16       // blocks per group (8 layer1 + 8 layer2)

// ---------------- workspace layout (bytes) ----------------
#define OFF_CNT   0ull                     // 16 counters * 128B pad = 2048
#define OFF_M1    2048ull                  // [2][256][128] f32
#define OFF_SPK1  (OFF_M1   + 262144ull)
#define OFF_M2    (OFF_SPK1 + 262144ull)
#define OFF_FEAT  (OFF_M2   + 262144ull)   // [256][128] f32
#define OFF_AB    (OFF_FEAT + 131072ull)   // a[64], b[64]
#define OFF_PART  (OFF_AB   + 512ull)      // [2304][64][2] f32
#define OFF_MASK  (OFF_PART + 1179648ull)  // [2000][256] u64
#define ZERO_WORDS 197120                  // counters + 3 state bufs

// ============================================================
// K0: zero counters + state double-buffers (re-run every launch
// so graph replays are deterministic)
// ============================================================
__global__ __launch_bounds__(256) void k0_zero(unsigned* ws) {
  int i = blockIdx.x * 256 + threadIdx.x;
  if (i < ZERO_WORDS) ws[i] = 0u;
}

// ============================================================
// K1: conv1d (recomputed) -> per-(b,tile) partial sum/sumsq for BN
// block: 256 threads = 4 waves; wave = 64 co lanes; wave tq covers 60 t
// ============================================================
__global__ __launch_bounds__(256) void k1_stats(const float* __restrict__ x,
                                                const float* __restrict__ cw,
                                                float* __restrict__ part) {
  __shared__ float xLds[244 * CIN];
  __shared__ float cwLds[64 * 70];
  __shared__ float red[2][4][64];
  const int b = blockIdx.x, tile = blockIdx.y;
  const int base = tile * 240;
  for (int f = threadIdx.x; f < 244 * CIN; f += 256) {
    int u = f / CIN, ci = f - u * CIN;
    int tp = base + u - 2;
    xLds[f] = (tp >= 0 && tp < TSTEPS) ? x[((size_t)tp * NB + b) * CIN + ci] : 0.0f;
  }
  for (int f = threadIdx.x; f < 64 * 70; f += 256) cwLds[f] = cw[f];
  __syncthreads();

  const int co = threadIdx.x & 63, tq = threadIdx.x >> 6;
  float cwr[70];
#pragma unroll
  for (int s = 0; s < 70; ++s) cwr[s] = cwLds[co * 70 + s];
  float xw[5][CIN];
  const int u0 = tq * 60;
#pragma unroll
  for (int r = 0; r < 4; ++r)
#pragma unroll
    for (int ci = 0; ci < CIN; ++ci) xw[r][ci] = xLds[(u0 + r) * CIN + ci];

  float s1 = 0.0f, s2 = 0.0f;
  const int tbase = base + tq * 60;
  for (int i5 = 0; i5 < 60; i5 += 5) {
#pragma unroll
    for (int s = 0; s < 5; ++s) {
#pragma unroll
      for (int ci = 0; ci < CIN; ++ci)
        xw[(s + 4) % 5][ci] = xLds[(u0 + i5 + s + 4) * CIN + ci];
      float y = 0.0f;
#pragma unroll
      for (int kk = 0; kk < 5; ++kk)
#pragma unroll
        for (int ci = 0; ci < CIN; ++ci)
          y += xw[(s + kk) % 5][ci] * cwr[ci * 5 + kk];
      if (tbase + i5 + s < TSTEPS) { s1 += y; s2 += y * y; }
    }
  }
  red[0][tq][co] = s1; red[1][tq][co] = s2;
  __syncthreads();
  if (threadIdx.x < 64) {
    float a1 = red[0][0][co] + red[0][1][co] + red[0][2][co] + red[0][3][co];
    float a2 = red[1][0][co] + red[1][1][co] + red[1][2][co] + red[1][3][co];
    int blk = tile * NB + b;
    part[blk * 128 + co * 2 + 0] = a1;
    part[blk * 128 + co * 2 + 1] = a2;
  }
}

// K1b: deterministic fixed-order reduction of partials -> a[co], b[co]
__global__ void k1b_reduce(const float* __restrict__ gamma, const float* __restrict__ beta,
                           const float* __restrict__ part, float* __restrict__ ab) {
  int co = threadIdx.x;
  if (co >= 64) return;
  float s1 = 0.0f, s2 = 0.0f;
  for (int blk = 0; blk < 9 * NB; ++blk) {
    s1 += part[blk * 128 + co * 2 + 0];
    s2 += part[blk * 128 + co * 2 + 1];
  }
  const float N = (float)TSTEPS * (float)NB;
  float mu = s1 / N;
  float var = s2 / N - mu * mu;
  float rstd = 1.0f / sqrtf(var + 1e-5f);
  float a = gamma[co] * rstd;
  ab[co] = a;
  ab[64 + co] = beta[co] - mu * a;
}

// ============================================================
// K2: conv1d again -> BN -> spike -> pack 64 channel bits into u64 per (t,b)
// ============================================================
__global__ __launch_bounds__(256) void k2_spike(const float* __restrict__ x,
                                                const float* __restrict__ cw,
                                                const float* __restrict__ thrp,
                                                const float* __restrict__ ab,
                                                unsigned long long* __restrict__ masks) {
  __shared__ float xLds[244 * CIN];
  __shared__ float cwLds[64 * 70];
  const int b = blockIdx.x, tile = blockIdx.y;
  const int base = tile * 240;
  for (int f = threadIdx.x; f < 244 * CIN; f += 256) {
    int u = f / CIN, ci = f - u * CIN;
    int tp = base + u - 2;
    xLds[f] = (tp >= 0 && tp < TSTEPS) ? x[((size_t)tp * NB + b) * CIN + ci] : 0.0f;
  }
  for (int f = threadIdx.x; f < 64 * 70; f += 256) cwLds[f] = cw[f];
  __syncthreads();

  const int co = threadIdx.x & 63, tq = threadIdx.x >> 6;
  const float thr = thrp[0];
  const float aC = ab[co], bC = ab[64 + co];
  float cwr[70];
#pragma unroll
  for (int s = 0; s < 70; ++s) cwr[s] = cwLds[co * 70 + s];
  float xw[5][CIN];
  const int u0 = tq * 60;
#pragma unroll
  for (int r = 0; r < 4; ++r)
#pragma unroll
    for (int ci = 0; ci < CIN; ++ci) xw[r][ci] = xLds[(u0 + r) * CIN + ci];

  const int tbase = base + tq * 60;
  for (int i5 = 0; i5 < 60; i5 += 5) {
#pragma unroll
    for (int s = 0; s < 5; ++s) {
#pragma unroll
      for (int ci = 0; ci < CIN; ++ci)
        xw[(s + 4) % 5][ci] = xLds[(u0 + i5 + s + 4) * CIN + ci];
      float y = 0.0f;
#pragma unroll
      for (int kk = 0; kk < 5; ++kk)
#pragma unroll
        for (int ci = 0; ci < CIN; ++ci)
          y += xw[(s + kk) % 5][ci] * cwr[ci * 5 + kk];
      int t = tbase + i5 + s;
      if (t < TSTEPS) {
        float bn = y * aC + bC;
        unsigned long long m = __ballot(bn - thr > 0.0f);  // lane i = channel i
        if (co == 0) masks[(size_t)t * NB + b] = m;
      }
    }
  }
}

// ============================================================
// KP: persistent two-layer SLSTM. 256 blocks = 16 groups x 16 roles.
// role 0..7  : layer1, h-chunk of 16 (computes step t = p,   p in [0,2000))
// role 8..15 : layer2, h-chunk of 16 (computes step t = p-1, p in [1,2000])
// One group barrier per phase; state exchanged via agent-scope atomics,
// double-buffered by phase parity.
// ============================================================
__global__ __launch_bounds__(512) void kp_lstm(char* ws,
    const float* __restrict__ w_ih1, const float* __restrict__ w_hh1,
    const float* __restrict__ b_ih1, const float* __restrict__ b_hh1,
    const float* __restrict__ thr1p,
    const float* __restrict__ w_ih2, const float* __restrict__ w_hh2,
    const float* __restrict__ b_ih2, const float* __restrict__ b_hh2,
    const float* __restrict__ thr2p) {
  // w layout: [jj][k], jj = gate*16 + h16, with 16B-unit XOR swizzle on k
  __shared__ __align__(16) float wLds[64 * 256];
  // A operand: [k][16 rows], float4-quad swizzled by (k&3)
  __shared__ __align__(16) float mTf[256 * 16];
  __shared__ float redBuf[8][16][64];
  __shared__ float synLds[16][16];
  __shared__ float memLds[16][16];
  __shared__ float biasLds[64];

  const int tid = threadIdx.x;
  const int bid = blockIdx.x;
  const int g = bid >> 4;        // group = consecutive bids -> no-deadlock pigeonhole
  const int role = bid & 15;
  const int hc = role & 7;
  const bool isL1 = role < 8;
  const int KD = isL1 ? 192 : 256;   // L1: 64 spike + 128 mem1 ; L2: 128 spk1 + 128 mem2

  unsigned* cnt = (unsigned*)(ws + OFF_CNT) + (size_t)g * 32;
  float* m1buf = (float*)(ws + OFF_M1);
  float* s1buf = (float*)(ws + OFF_SPK1);
  float* m2buf = (float*)(ws + OFF_M2);
  float* feat  = (float*)(ws + OFF_FEAT);
  const unsigned long long* masks = (const unsigned long long*)(ws + OFF_MASK);

  // ---- one-time: weights -> LDS (swizzled), bias, zero private state ----
  for (int f = tid; f < KD * 64; f += 512) {
    int k = f >> 6, jj = f & 63;
    int grow = (jj >> 4) * 128 + hc * 16 + (jj & 15);
    float v;
    if (isL1) v = (k < 64)  ? w_ih1[grow * 64 + k]  : w_hh1[grow * 128 + (k - 64)];
    else      v = (k < 128) ? w_ih2[grow * 128 + k] : w_hh2[grow * 128 + (k - 128)];
    wLds[jj * KD + (k ^ ((jj & 7) << 2))] = v;
  }
  if (tid < 64) {
    int grow = (tid >> 4) * 128 + hc * 16 + (tid & 15);
    biasLds[tid] = isL1 ? (b_ih1[grow] + b_hh1[grow]) : (b_ih2[grow] + b_hh2[grow]);
  }
  if (tid < 256) { synLds[tid >> 4][tid & 15] = 0.0f; memLds[tid >> 4][tid & 15] = 0.0f; }
  const float thr = isL1 ? thr1p[0] : thr2p[0];
  __syncthreads();

  const int lane = tid & 63, wv = tid >> 6;
  const int j16 = lane & 15, rs = lane >> 4;     // lane = (rs rowquad, j16 h)
  const int kslice = KD >> 3;                    // 24 / 32, both %4==0
  const int ks = kslice * wv;
  float facc = 0.0f;

  for (int p = 0; p <= TSTEPS; ++p) {
    const bool active = isL1 ? (p < TSTEPS) : (p >= 1);
    if (active) {
      const int rb = (p + 1) & 1, wb = p & 1;
      // ---- stage A into mTf ----
      if (isL1) {
        for (int f = tid; f < 64 * 16; f += 512) {
          int r = f >> 6, c = f & 63;
          unsigned long long m = masks[(size_t)p * NB + g * RG + r];
          float v = (float)((m >> c) & 1ull);
          mTf[c * 16 + ((((r >> 2) ^ (c & 3)) << 2)) + (r & 3)] = v;
        }
        const float* src = m1buf + (size_t)rb * NB * HID;
        for (int f = tid; f < RG * HID; f += 512) {
          int r = f >> 7, k = f & 127;
          float v = __hip_atomic_load(&src[(g * RG + r) * HID + k],
                                      __ATOMIC_RELAXED, __HIP_MEMORY_SCOPE_AGENT);
          int kk = 64 + k;
          mTf[kk * 16 + ((((r >> 2) ^ (kk & 3)) << 2)) + (r & 3)] = v;
        }
      } else {
        const float* srcs = s1buf + (size_t)rb * NB * HID;
        const float* srcm = m2buf + (size_t)rb * NB * HID;
        for (int f = tid; f < RG * HID; f += 512) {
          int r = f >> 7, k = f & 127;
          float v = __hip_atomic_load(&srcs[(g * RG + r) * HID + k],
                                      __ATOMIC_RELAXED, __HIP_MEMORY_SCOPE_AGENT);
          mTf[k * 16 + ((((r >> 2) ^ (k & 3)) << 2)) + (r & 3)] = v;
        }
        for (int f = tid; f < RG * HID; f += 512) {
          int r = f >> 7, k = f & 127;
          float v = __hip_atomic_load(&srcm[(g * RG + r) * HID + k],
                                      __ATOMIC_RELAXED, __HIP_MEMORY_SCOPE_AGENT);
          int kk = 128 + k;
          mTf[kk * 16 + ((((r >> 2) ^ (kk & 3)) << 2)) + (r & 3)] = v;
        }
      }
      __syncthreads();

      // ---- gate GEMM over this wave's k-slice; acc[gate][rowquad elem] ----
      float acc[4][4];
#pragma unroll
      for (int a = 0; a < 4; ++a) { acc[a][0] = 0; acc[a][1] = 0; acc[a][2] = 0; acc[a][3] = 0; }
#pragma unroll 2
      for (int k4 = ks; k4 < ks + kslice; k4 += 4) {
        float4 aa[4];
#pragma unroll
        for (int e = 0; e < 4; ++e)
          aa[e] = *(const float4*)&mTf[(k4 + e) * 16 + ((rs ^ ((k4 + e) & 3)) << 2)];
        float4 wq[4];
#pragma unroll
        for (int a = 0; a < 4; ++a)
          wq[a] = *(const float4*)&wLds[(a * 16 + j16) * KD + (k4 ^ ((j16 & 7) << 2))];
#pragma unroll
        for (int a = 0; a < 4; ++a) {
          acc[a][0] += wq[a].x * aa[0].x; acc[a][1] += wq[a].x * aa[0].y;
          acc[a][2] += wq[a].x * aa[0].z; acc[a][3] += wq[a].x * aa[0].w;
          acc[a][0] += wq[a].y * aa[1].x; acc[a][1] += wq[a].y * aa[1].y;
          acc[a][2] += wq[a].y * aa[1].z; acc[a][3] += wq[a].y * aa[1].w;
          acc[a][0] += wq[a].z * aa[2].x; acc[a][1] += wq[a].z * aa[2].y;
          acc[a][2] += wq[a].z * aa[2].z; acc[a][3] += wq[a].z * aa[2].w;
          acc[a][0] += wq[a].w * aa[3].x; acc[a][1] += wq[a].w * aa[3].y;
          acc[a][2] += wq[a].w * aa[3].z; acc[a][3] += wq[a].w * aa[3].w;
        }
      }
#pragma unroll
      for (int a = 0; a < 4; ++a)
#pragma unroll
        for (int rr = 0; rr < 4; ++rr)
          redBuf[wv][rs * 4 + rr][a * 16 + j16] = acc[a][rr];
      __syncthreads();

      // ---- elementwise cell update + publish (deterministic 8-way sum) ----
      if (tid < 256) {
        const int r = tid >> 4, h = tid & 15;
        float gate[4];
#pragma unroll
        for (int a = 0; a < 4; ++a) {
          float s = biasLds[a * 16 + h];
#pragma unroll
          for (int w8 = 0; w8 < 8; ++w8) s += redBuf[w8][r][a * 16 + h];
          gate[a] = s;
        }
        const float synv = synLds[r][h];
        const float memv = memLds[r][h];
        const float rst = (memv - thr > 0.0f) ? 1.0f : 0.0f;
        const float ig = 1.0f / (1.0f + expf(-gate[0]));
        const float fg = 1.0f / (1.0f + expf(-gate[1]));
        const float gg = tanhf(gate[2]);
        const float og = 1.0f / (1.0f + expf(-gate[3]));
        const float cn = fg * synv + ig * gg;
        const float hn = og * tanhf(cn);
        const float mn = hn - rst * thr;
        synLds[r][h] = cn;
        memLds[r][h] = mn;
        const int rowg = g * RG + r;
        const int hg = hc * 16 + h;
        if (isL1) {
          const float spk = (mn - thr > 0.0f) ? 1.0f : 0.0f;
          __hip_atomic_store(&m1buf[(size_t)wb * NB * HID + rowg * HID + hg], mn,
                             __ATOMIC_RELAXED, __HIP_MEMORY_SCOPE_AGENT);
          __hip_atomic_store(&s1buf[(size_t)wb * NB * HID + rowg * HID + hg], spk,
                             __ATOMIC_RELAXED, __HIP_MEMORY_SCOPE_AGENT);
        } else {
          __hip_atomic_store(&m2buf[(size_t)wb * NB * HID + rowg * HID + hg], mn,
                             __ATOMIC_RELAXED, __HIP_MEMORY_SCOPE_AGENT);
          facc += mn;
        }
      }
    }
    // ---- group barrier (monotonic counter; syncthreads drains vmcnt first) ----
    __syncthreads();
    if (tid == 0) {
      __hip_atomic_fetch_add(cnt, 1u, __ATOMIC_RELEASE, __HIP_MEMORY_SCOPE_AGENT);
      const unsigned tgt = (unsigned)(BPG * (p + 1));
      while (__hip_atomic_load(cnt, __ATOMIC_RELAXED, __HIP_MEMORY_SCOPE_AGENT) < tgt)
        __builtin_amdgcn_s_sleep(2);
      __threadfence();
    }
    __syncthreads();
  }

  if (!isL1 && tid < 256) {
    const int r = tid >> 4, h = tid & 15;
    feat[(g * RG + r) * HID + hc * 16 + h] = facc * (1.0f / (float)TSTEPS);
  }
}

// ============================================================
// K3: head — gesture + (binary) domain_hidden -> domain
// ============================================================
__global__ __launch_bounds__(128) void k3_head(const float* __restrict__ feat,
    const float* __restrict__ gw, const float* __restrict__ gb,
    const float* __restrict__ d1w, const float* __restrict__ d1b,
    const float* __restrict__ thrdp,
    const float* __restrict__ d2w, const float* __restrict__ d2b,
    float* __restrict__ out) {
  __shared__ float fL[128];
  __shared__ float dh[64];
  const int b = blockIdx.x, t = threadIdx.x;
  fL[t] = feat[b * 128 + t];
  __syncthreads();
  if (t < 64) {
    float s = d1b[t];
    for (int k = 0; k < 128; ++k) s += d1w[t * 128 + k] * fL[k];
    dh[t] = (s - thrdp[0] > 0.0f) ? 1.0f : 0.0f;
  }
  __syncthreads();
  if (t < 8) {
    float s = gb[t];
    for (int k = 0; k < 128; ++k) s += gw[t * 128 + k] * fL[k];
    out[b * 8 + t] = s;
  }
  if (t >= 64 && t < 74) {
    const int o = t - 64;
    float s = d2b[o];
    for (int k = 0; k < 64; ++k) s += d2w[o * 64 + k] * dh[k];
    out[2048 + b * 10 + o] = s;
  }
}

// ============================================================
extern "C" void kernel_launch(void* const* d_in, const int* in_sizes, int n_in,
                              void* d_out, int out_size, void* d_ws, size_t ws_size,
                              hipStream_t stream) {
  const float* x      = (const float*)d_in[0];
  const float* conv_w = (const float*)d_in[1];
  const float* bn_g   = (const float*)d_in[2];
  const float* bn_b   = (const float*)d_in[3];
  const float* thrl1  = (const float*)d_in[4];
  const float* w_ih1  = (const float*)d_in[5];
  const float* w_hh1  = (const float*)d_in[6];
  const float* b_ih1  = (const float*)d_in[7];
  const float* b_hh1  = (const float*)d_in[8];
  const float* thr1   = (const float*)d_in[9];
  const float* w_ih2  = (const float*)d_in[10];
  const float* w_hh2  = (const float*)d_in[11];
  const float* b_ih2  = (const float*)d_in[12];
  const float* b_hh2  = (const float*)d_in[13];
  const float* thr2   = (const float*)d_in[14];
  const float* fc_g_w = (const float*)d_in[15];
  const float* fc_g_b = (const float*)d_in[16];
  const float* fc_d1w = (const float*)d_in[17];
  const float* fc_d1b = (const float*)d_in[18];
  const float* thrdom = (const float*)d_in[19];
  const float* fc_d2w = (const float*)d_in[20];
  const float* fc_d2b = (const float*)d_in[21];
  float* out = (float*)d_out;
  char* ws = (char*)d_ws;

  k0_zero<<<(ZERO_WORDS + 255) / 256, 256, 0, stream>>>((unsigned*)ws);
  k1_stats<<<dim3(NB, 9), 256, 0, stream>>>(x, conv_w, (float*)(ws + OFF_PART));
  k1b_reduce<<<1, 64, 0, stream>>>(bn_g, bn_b, (const float*)(ws + OFF_PART),
                                   (float*)(ws + OFF_AB));
  k2_spike<<<dim3(NB, 9), 256, 0, stream>>>(x, conv_w, thrl1,
                                            (const float*)(ws + OFF_AB),
                                            (unsigned long long*)(ws + OFF_MASK));
  kp_lstm<<<NGRP * BPG, 512, 0, stream>>>(ws, w_ih1, w_hh1, b_ih1, b_hh1, thr1,
                                          w_ih2, w_hh2, b_ih2, b_hh2, thr2);
  k3_head<<<NB, 128, 0, stream>>>((const float*)(ws + OFF_FEAT), fc_g_w, fc_g_b,
                                  fc_d1w, fc_d1b, thrdom, fc_d2w, fc_d2b, out);
}